// Round 12
// baseline (646.020 us; speedup 1.0000x reference)
//
#include <hip/hip_runtime.h>
#include <math.h>

#define VOCAB 4096
#define EMBED 64
#define OBSD  128
#define HIDD  512
#define BNR   4096        // batch rows (1024*4)
#define ZR    65536       // token rows (BNR*16)
#define ZD    1024        // 16*EMBED
#define NCHUNK 4
#define CHSZ  (VOCAB / NCHUNK)   // 1024 codes per chunk
#define TCODES 64                // codes per LDS tile
#define NTILES (CHSZ / TCODES)   // 16 tiles per chunk

// dist computes z-split scores (zhi+zlo vs unsplit c): ε = |z·Δc| ≈ 3.5e-4 rms
// scaled. Margin 4e-3 ≈ 7σ of gap noise; rows with approx top-2 gap < margin
// get an exact fp64 rescan (rescue v2, batched). Proven r9-r11.
#define MARGIN_SCALED 4.0e-3f

// dist LDS layout strides (halfs), padded (proven r5-r11)
#define SSTR 136
#define GSTR (8 * SSTR)          // 1088 halfs per 16-code group
#define TYPSZ (4 * GSTR)         // 4352 halfs per tile buffer (hi only)

#define RB 8                     // rescue rows per batch

typedef _Float16 half8  __attribute__((ext_vector_type(8)));
typedef _Float16 half4  __attribute__((ext_vector_type(4)));
typedef short    bf16x8 __attribute__((ext_vector_type(8)));
typedef float    f32x4  __attribute__((ext_vector_type(4)));

__device__ __forceinline__ f32x4 mfma_f16(half8 a, half8 b, f32x4 c){
  return __builtin_amdgcn_mfma_f32_16x16x32_f16(a,b,c,0,0,0);
}
__device__ __forceinline__ f32x4 mfma_bf(bf16x8 a, bf16x8 b, f32x4 c){
  return __builtin_amdgcn_mfma_f32_16x16x32_bf16(a,b,c,0,0,0);
}
__device__ __forceinline__ unsigned short f2bf(float f){
  union{float f; unsigned u;} x; x.f=f;
  unsigned u = x.u + 0x7fffu + ((x.u>>16)&1u);
  return (unsigned short)(u>>16);
}
__device__ __forceinline__ float bf2f(unsigned short h){
  union{unsigned u; float f;} x; x.u = ((unsigned)h)<<16; return x.f;
}
__device__ __forceinline__ void split3(float w, unsigned short& b1,
                                       unsigned short& b2, unsigned short& b3){
  b1 = f2bf(w); float r  = w - bf2f(b1);
  b2 = f2bf(r); float r2 = r - bf2f(b2);
  b3 = f2bf(r2);
}
__device__ __forceinline__ bf16x8 ldbf(const unsigned short* p){
  return *(const bf16x8*)(const void*)p;
}

// ---------- fused prep: cb f16 + cbT + fp64 bias + weight splits + rcnt zero
// r12: weight transposes iterate SOURCE-major (coalesced reads, strided writes
// absorbed by L2 write-combining) — r11's strided 4B reads were latency-bound.
__global__ __launch_bounds__(256) void prep_all_kernel(
    const float* __restrict__ cb, _Float16* __restrict__ chi,
    float* __restrict__ bcol, double* __restrict__ bcold,
    float* __restrict__ cbT,
    const float* __restrict__ ew1, unsigned short* __restrict__ w1t1,
    unsigned short* __restrict__ w1t2, unsigned short* __restrict__ w1t3,
    const float* __restrict__ ew2, unsigned short* __restrict__ w2t1,
    unsigned short* __restrict__ w2t2, unsigned short* __restrict__ w2t3,
    const float* __restrict__ obs, unsigned short* __restrict__ o1,
    unsigned short* __restrict__ o2, unsigned short* __restrict__ o3,
    const float* __restrict__ dw1, unsigned short* __restrict__ d1t,
    const float* __restrict__ dw2, unsigned short* __restrict__ d2t,
    int* __restrict__ rcnt)
{
  const int b = blockIdx.x;
  const int t = threadIdx.x;
  if (b == 0 && t == 0) *rcnt = 0;
  if (b < 16) {
    int j = b * 256 + t;
    double s = 0.0;
    #pragma unroll 8
    for (int d = 0; d < EMBED; ++d) {
      float c = cb[j * EMBED + d];
      s += (double)c * (double)c;
      chi[j * EMBED + d] = (_Float16)(c * 4096.0f);   // pow2 scale exact
      cbT[(size_t)d * VOCAB + j] = c;                 // coalesced write
    }
    double bd = -0.5 * s * 4096.0;
    bcold[j] = bd;
    bcol[j] = (float)bd;
  } else if (b < 272) {
    // ew1 [OBSD][HIDD] -> 3-split [HIDD][OBSD]; source-major read
    int e = (b - 16) * 256 + t;          // e = k*HIDD + n
    int k = e / HIDD, n = e % HIDD;
    split3(ew1[e], w1t1[n * OBSD + k], w1t2[n * OBSD + k], w1t3[n * OBSD + k]);
  } else if (b < 2320) {
    // ew2 [HIDD][ZD] -> 3-split [ZD][HIDD]; source-major read
    int e = (b - 272) * 256 + t;         // e = k*ZD + n
    int k = e / ZD, n = e % ZD;
    split3(ew2[e], w2t1[n * HIDD + k], w2t2[n * HIDD + k], w2t3[n * HIDD + k]);
  } else if (b < 4368) {
    // obs elementwise 3-split (already coalesced)
    int e = (b - 2320) * 256 + t;
    split3(obs[e], o1[e], o2[e], o3[e]);
  } else if (b < 6416) {
    // dw1 [ZD][HIDD] -> bf16 [HIDD][ZD]; source-major read
    int e = (b - 4368) * 256 + t;        // e = k*HIDD + n
    int k = e / HIDD, n = e % HIDD;
    d1t[(size_t)n * ZD + k] = f2bf(dw1[e]);
  } else {
    // dw2 [HIDD][OBSD] -> bf16 [OBSD][HIDD]; source-major read
    int e = (b - 6416) * 256 + t;        // e = k*OBSD + n
    int k = e / OBSD, n = e % OBSD;
    d2t[(size_t)n * HIDD + k] = f2bf(dw2[e]);
  }
}

// ---------- LDS-staged GEMM template (enc1/enc2/dec1), proven r10/r11.
// OUT: 0 = relu+split3(H1..H3), 1 = Z + f16 hi/lo (Zhi,Zlo), 2 = relu+bf16(H1)
template<int NSPLIT, int MS, bool RELU, int OUT>
__global__ __launch_bounds__(512) void gemm_lds_kernel(
    const unsigned short* __restrict__ A1, const unsigned short* __restrict__ A2,
    const unsigned short* __restrict__ A3,
    const unsigned short* __restrict__ B1, const unsigned short* __restrict__ B2,
    const unsigned short* __restrict__ B3,
    const float* __restrict__ bias, int M, int N, int K,
    unsigned short* __restrict__ H1, unsigned short* __restrict__ H2,
    unsigned short* __restrict__ H3,
    float* __restrict__ Z, _Float16* __restrict__ Zhi, _Float16* __restrict__ Zlo)
{
  constexpr int BM  = MS * 32;
  constexpr int ASZ = BM * 40;          // halfs per A split
  constexpr int BSZ = 128 * 40;         // halfs per B split
  constexpr int ACH = BM * 4;           // 16B chunks per A split
  constexpr int TCH = ACH + 512;        // + B chunks (128*4)
  __shared__ unsigned short lds[NSPLIT * (ASZ + BSZ)];

  const int tid  = threadIdx.x;
  const int wave = tid >> 6;
  const int lane = tid & 63;
  const int l15  = lane & 15;
  const int lg   = lane >> 4;
  const int wm   = wave >> 2;           // 0..1
  const int wn   = wave & 3;            // 0..3
  const int m0   = blockIdx.x * BM;
  const int n0   = blockIdx.y * 128;

  const unsigned short* Aps[3] = {A1, A2, A3};
  const unsigned short* Bps[3] = {B1, B2, B3};

  // staging slots: thread handles chunks {tid, tid+512} of the (A|B) space
  size_t goff[2]; int lb[2], pst[2]; bool valid[2], isA[2];
  #pragma unroll
  for (int sl = 0; sl < 2; ++sl) {
    int c = tid + sl * 512;
    valid[sl] = c < TCH;
    bool a = c < ACH;
    isA[sl] = a;
    int cr = a ? c : (c - ACH);
    if (!valid[sl]) cr = 0;
    int row = cr >> 2, o16 = cr & 3;
    goff[sl] = (size_t)(a ? m0 + row : n0 + row) * K + o16 * 8;
    lb[sl]   = (a ? 0 : NSPLIT * ASZ) + row * 40 + o16 * 8;
    pst[sl]  = a ? ASZ : BSZ;
  }

  // prologue: stage k-step 0
  #pragma unroll
  for (int sl = 0; sl < 2; ++sl) if (valid[sl]) {
    #pragma unroll
    for (int p = 0; p < NSPLIT; ++p)
      *(bf16x8*)(void*)&lds[lb[sl] + p * pst[sl]] =
          ldbf((isA[sl] ? Aps[p] : Bps[p]) + goff[sl]);
  }
  __syncthreads();

  double accd[MS][2][4];
  f32x4  accf[MS][2];
  #pragma unroll
  for (int ms = 0; ms < MS; ++ms)
    #pragma unroll
    for (int ns = 0; ns < 2; ++ns) {
      accf[ms][ns] = (f32x4){0.f, 0.f, 0.f, 0.f};
      #pragma unroll
      for (int r = 0; r < 4; ++r) accd[ms][ns][r] = 0.0;
    }

  const int KS = K / 32;
  for (int step = 0; step < KS; ++step) {
    bf16x8 nv[NSPLIT][2];
    const bool pre = (step + 1 < KS);
    if (pre) {
      #pragma unroll
      for (int sl = 0; sl < 2; ++sl) if (valid[sl]) {
        #pragma unroll
        for (int p = 0; p < NSPLIT; ++p)
          nv[p][sl] = ldbf((isA[sl] ? Aps[p] : Bps[p]) + goff[sl]
                           + (size_t)(step + 1) * 32);
      }
    }

    bf16x8 af[NSPLIT][MS], bfr[NSPLIT][2];
    #pragma unroll
    for (int ms = 0; ms < MS; ++ms) {
      const int ar = (wm * MS * 16 + ms * 16 + l15) * 40 + lg * 8;
      #pragma unroll
      for (int p = 0; p < NSPLIT; ++p)
        af[p][ms] = *(const bf16x8*)(const void*)&lds[p * ASZ + ar];
    }
    #pragma unroll
    for (int ns = 0; ns < 2; ++ns) {
      const int br = (wn * 32 + ns * 16 + l15) * 40 + lg * 8;
      #pragma unroll
      for (int p = 0; p < NSPLIT; ++p)
        bfr[p][ns] = *(const bf16x8*)(const void*)&lds[NSPLIT * ASZ + p * BSZ + br];
    }

    #pragma unroll
    for (int ms = 0; ms < MS; ++ms)
      #pragma unroll
      for (int ns = 0; ns < 2; ++ns) {
        if constexpr (NSPLIT == 3) {
          f32x4 acc = {0.f, 0.f, 0.f, 0.f};
          // smallest terms first, dominant a1*b1 last (order == r9-r11 enc)
          acc = mfma_bf(af[0][ms], bfr[2][ns], acc);
          acc = mfma_bf(af[1][ms], bfr[1][ns], acc);
          acc = mfma_bf(af[2][ms], bfr[0][ns], acc);
          acc = mfma_bf(af[0][ms], bfr[1][ns], acc);
          acc = mfma_bf(af[1][ms], bfr[0][ns], acc);
          acc = mfma_bf(af[0][ms], bfr[0][ns], acc);
          #pragma unroll
          for (int r = 0; r < 4; ++r) accd[ms][ns][r] += (double)acc[r];
        } else {
          accf[ms][ns] = mfma_bf(af[0][ms], bfr[0][ns], accf[ms][ns]);
        }
      }

    __syncthreads();              // all waves done reading lds
    if (pre) {
      #pragma unroll
      for (int sl = 0; sl < 2; ++sl) if (valid[sl]) {
        #pragma unroll
        for (int p = 0; p < NSPLIT; ++p)
          *(bf16x8*)(void*)&lds[lb[sl] + p * pst[sl]] = nv[p][sl];
      }
    }
    __syncthreads();              // next step visible
  }

  #pragma unroll
  for (int ms = 0; ms < MS; ++ms)
    #pragma unroll
    for (int ns = 0; ns < 2; ++ns)
      #pragma unroll
      for (int r = 0; r < 4; ++r) {
        int row = m0 + wm * MS * 16 + ms * 16 + lg * 4 + r;
        int col = n0 + wn * 32 + ns * 16 + l15;
        float v = (NSPLIT == 3 ? (float)accd[ms][ns][r] : accf[ms][ns][r])
                  + bias[col];
        if constexpr (RELU) v = v > 0.f ? v : 0.f;
        size_t o = (size_t)row * N + col;
        if constexpr (OUT == 0) {
          split3(v, H1[o], H2[o], H3[o]);
        } else if constexpr (OUT == 1) {
          Z[o] = v;
          _Float16 hi = (_Float16)v;
          Zhi[o] = hi;
          Zlo[o] = (_Float16)(v - (float)hi);
        } else {
          H1[o] = f2bf(v);
        }
      }
}

// ---------- dec2 GEMM: plain bf16 1-pass MFMA, direct loads (small)
template<bool RELU, bool OUTBF>
__global__ __launch_bounds__(256) void dec_mfma_kernel(
    const unsigned short* __restrict__ A, const unsigned short* __restrict__ B,
    const float* __restrict__ bias, int M, int N, int K,
    unsigned short* __restrict__ Obf, float* __restrict__ Of)
{
  const int tid  = threadIdx.x;
  const int wave = tid >> 6;
  const int lane = tid & 63;
  const int l15  = lane & 15;
  const int lg   = lane >> 4;
  const int m0 = blockIdx.x * 64 + (wave >> 1) * 32;
  const int n0 = blockIdx.y * 64 + (wave & 1) * 32;

  f32x4 acc[2][2] = {};
  for (int k0 = 0; k0 < K; k0 += 32) {
    bf16x8 a[2], b[2];
    #pragma unroll
    for (int ms = 0; ms < 2; ++ms)
      a[ms] = ldbf(A + (size_t)(m0 + ms * 16 + l15) * K + k0 + lg * 8);
    #pragma unroll
    for (int ns = 0; ns < 2; ++ns)
      b[ns] = ldbf(B + (size_t)(n0 + ns * 16 + l15) * K + k0 + lg * 8);
    #pragma unroll
    for (int ms = 0; ms < 2; ++ms)
      #pragma unroll
      for (int ns = 0; ns < 2; ++ns)
        acc[ms][ns] = mfma_bf(a[ms], b[ns], acc[ms][ns]);
  }
  #pragma unroll
  for (int ms = 0; ms < 2; ++ms)
    #pragma unroll
    for (int ns = 0; ns < 2; ++ns)
      #pragma unroll
      for (int r = 0; r < 4; ++r) {
        int row = m0 + ms * 16 + lg * 4 + r;
        int col = n0 + ns * 16 + l15;
        float v = acc[ms][ns][r] + bias[col];
        if constexpr (RELU) v = v > 0.f ? v : 0.f;
        if constexpr (OUTBF) Obf[(size_t)row * N + col] = f2bf(v);
        else                 Of[(size_t)row * N + col] = v;
      }
}

// ---------- VQ distance: z-split (zhi+zlo) vs unsplit c — 4-MFMA chain.
// r12: 64 rows/wave (4 subtiles) — doubles MFMA per ds_read (1:8) to feed the
// matrix pipe (r11 PMC: MfmaUtil 34% with LDS/issue-bound 4-MFMA-per-2-read
// groups). 16-wave block kept (r6's rows-64 failure was its 4-wave block).
// Grid (64,4) = 256 blocks = 1/CU, single round. Single barrier/tile (r11).
// NOTE: no min-waves clause — a VGPR cap makes the compiler demote the
// loop-invariant z fragments to per-iteration reloads (r3: 2 GB HBM, 3x slower).
__global__ __launch_bounds__(1024) void dist_kernel(
    const _Float16* __restrict__ zhi, const _Float16* __restrict__ zlo,
    const _Float16* __restrict__ chi, const float* __restrict__ bcol,
    float2* __restrict__ pb2, int* __restrict__ pidx)
{
  __shared__ _Float16 sh[2][TYPSZ];      // [buf][padded 64-code tile]
  __shared__ float    sbc[CHSZ];

  const int tid  = threadIdx.x;
  const int wave = tid >> 6;
  const int lane = tid & 63;
  const int l15  = lane & 15;
  const int lg   = lane >> 4;
  const int rowW = blockIdx.x * 1024 + wave * 64;
  const int ch   = blockIdx.y;

  // z fragments: loop-invariant, stay in VGPRs (4 subtiles x 4 frags x 4 regs)
  half8 ah0[4], ah1[4], al0[4], al1[4];
  #pragma unroll
  for (int s = 0; s < 4; ++s) {
    const size_t base = (size_t)(rowW + s * 16 + l15) * EMBED + lg * 8;
    ah0[s] = *(const half8*)(zhi + base);
    ah1[s] = *(const half8*)(zhi + base + 32);
    al0[s] = *(const half8*)(zlo + base);
    al1[s] = *(const half8*)(zlo + base + 32);
  }

  const _Float16* gsrc = chi + (size_t)ch * CHSZ * EMBED;
  const int code = tid >> 4, rem = tid & 15, sl = rem >> 1, hf = rem & 1;
  const int ld = (code >> 4) * GSTR + sl * SSTR + (code & 15) * 8 + hf * 4;
  const size_t goff = (size_t)code * EMBED + sl * 8 + hf * 4;

  sbc[tid] = bcol[ch * CHSZ + tid];

  *(half4*)(&sh[0][ld]) = *(const half4*)(gsrc + goff);
  __syncthreads();

  float best[4][4], second[4][4];
  int   bidx[4][4];
  #pragma unroll
  for (int s = 0; s < 4; ++s)
    #pragma unroll
    for (int r = 0; r < 4; ++r) {
      best[s][r] = -INFINITY; second[s][r] = -INFINITY; bidx[s][r] = 0;
    }

  for (int tile = 0; tile < NTILES; ++tile) {
    const int buf = tile & 1;
    half4 v0 = {};
    if (tile + 1 < NTILES)
      v0 = *(const half4*)(gsrc + (size_t)(tile + 1) * (TCODES * EMBED) + goff);

    const _Float16* ph = &sh[buf][0];
    #pragma unroll
    for (int grp = 0; grp < 4; ++grp) {
      const int rb = grp * GSTR + l15 * 8;
      half8 bh0 = *(const half8*)(ph + rb + lg * SSTR);
      half8 bh1 = *(const half8*)(ph + rb + (4 + lg) * SSTR);
      const int cloc = tile * TCODES + grp * 16 + l15;
      const int col  = ch * CHSZ + cloc;
      const float vb = sbc[cloc];
      const f32x4 seed = {vb, vb, vb, vb};     // shared C operand, 16 chains
      #pragma unroll
      for (int s = 0; s < 4; ++s) {
        // small (zlo) terms first, dominant zhi last
        f32x4 acc = seed;
        acc = mfma_f16(al0[s], bh0, acc);
        acc = mfma_f16(al1[s], bh1, acc);
        acc = mfma_f16(ah0[s], bh0, acc);
        acc = mfma_f16(ah1[s], bh1, acc);
        #pragma unroll
        for (int r = 0; r < 4; ++r) {
          float v = acc[r];
          float sn = __builtin_amdgcn_fmed3f(second[s][r], best[s][r], v);
          bool gt = v > best[s][r];
          best[s][r] = gt ? v : best[s][r];
          bidx[s][r] = gt ? col : bidx[s][r];
          second[s][r] = sn;
        }
      }
    }
    // write next tile into the other buffer (safe: its last readers finished
    // before the previous iteration's barrier), then ONE barrier (r11).
    if (tile + 1 < NTILES)
      *(half4*)(&sh[buf ^ 1][ld]) = v0;
    __syncthreads();
  }

  // reduce (best,second,idx) across the 16 col-lanes (low 4 lane bits)
  #pragma unroll
  for (int m = 1; m <= 8; m <<= 1) {
    #pragma unroll
    for (int s = 0; s < 4; ++s)
      #pragma unroll
      for (int r = 0; r < 4; ++r) {
        float ob = __shfl_xor(best[s][r], m, 64);
        float os = __shfl_xor(second[s][r], m, 64);
        int   oi = __shfl_xor(bidx[s][r], m, 64);
        float mn = fminf(best[s][r], ob);
        second[s][r] = fmaxf(mn, fmaxf(second[s][r], os));
        if (ob > best[s][r]) { best[s][r] = ob; bidx[s][r] = oi; }
      }
  }

  if (l15 == 0) {
    #pragma unroll
    for (int s = 0; s < 4; ++s)
      #pragma unroll
      for (int r = 0; r < 4; ++r) {
        int row = rowW + s * 16 + lg * 4 + r;
        pb2 [(size_t)ch * ZR + row] = make_float2(best[s][r], second[s][r]);
        pidx[(size_t)ch * ZR + row] = bidx[s][r];
      }
  }
}

// ---------- merge chunk partials -> tokens + rescue list
__global__ __launch_bounds__(256) void merge_kernel(
    const float2* __restrict__ pb2, const int* __restrict__ pidx,
    int* __restrict__ tokens, int* __restrict__ rcnt, int* __restrict__ rrows)
{
  int r = blockIdx.x * 256 + threadIdx.x;
  float b = -INFINITY, s = -INFINITY;
  int bi = 0;
  #pragma unroll
  for (int c = 0; c < NCHUNK; ++c) {
    float2 p = pb2[(size_t)c * ZR + r];
    int    i = pidx[(size_t)c * ZR + r];
    if (p.x > b) { s = fmaxf(b, p.y); b = p.x; bi = i; }
    else         { s = fmaxf(s, p.x); }
  }
  tokens[r] = bi;
  if (b - s < MARGIN_SCALED) {
    int p = atomicAdd(rcnt, 1);
    if (p < ZR) rrows[p] = r;
  }
}

// ---------- rescue v2: exact fp64 rescan, batched (proven r9-r11)
__global__ __launch_bounds__(512) void rescue_kernel(
    const int* __restrict__ cnt, const int* __restrict__ rows,
    const float* __restrict__ z, const float* __restrict__ cbT,
    const double* __restrict__ bcold, int* __restrict__ tokens)
{
  __shared__ double zl[RB][EMBED];
  __shared__ int    ridx[RB];
  __shared__ double swv[8][RB];
  __shared__ int    swi[8][RB];

  int n = *cnt; if (n > ZR) n = ZR;
  int nb = (n + RB - 1) / RB;
  const int tid = threadIdx.x;

  for (int batch = blockIdx.x; batch < nb; batch += gridDim.x) {
    __syncthreads();
    if (tid < RB) {
      int e = batch * RB + tid;
      ridx[tid] = (e < n) ? rows[e] : -1;
    }
    __syncthreads();
    {
      int r = tid >> 6, k = tid & 63;
      int rr = ridx[r];
      zl[r][k] = (rr >= 0) ? (double)z[(size_t)rr * EMBED + k] : 0.0;
    }
    __syncthreads();

    double best[RB]; int bidx[RB];
    #pragma unroll
    for (int r = 0; r < RB; ++r) { best[r] = -1.0e300; bidx[r] = 0; }

    for (int c = 0; c < VOCAB / 512; ++c) {
      const int j = c * 512 + tid;
      double acc[RB] = {};
      #pragma unroll 16
      for (int k = 0; k < EMBED; ++k) {
        double cd = (double)cbT[(size_t)k * VOCAB + j];
        #pragma unroll
        for (int r = 0; r < RB; ++r)
          acc[r] = fma(cd, zl[r][k], acc[r]);
      }
      const double bc = bcold[j];
      #pragma unroll
      for (int r = 0; r < RB; ++r) {
        double s = 4096.0 * acc[r] + bc;
        if (s > best[r]) { best[r] = s; bidx[r] = j; }
      }
    }

    #pragma unroll
    for (int m = 1; m < 64; m <<= 1) {
      #pragma unroll
      for (int r = 0; r < RB; ++r) {
        double ov = __shfl_xor(best[r], m, 64);
        int    oi = __shfl_xor(bidx[r], m, 64);
        if (ov > best[r] || (ov == best[r] && oi < bidx[r])) {
          best[r] = ov; bidx[r] = oi;
        }
      }
    }
    const int wv = tid >> 6, ln = tid & 63;
    if (ln == 0)
      #pragma unroll
      for (int r = 0; r < RB; ++r) { swv[wv][r] = best[r]; swi[wv][r] = bidx[r]; }
    __syncthreads();
    if (tid < RB) {
      int r = tid;
      double bv = swv[0][r]; int bi = swi[0][r];
      #pragma unroll
      for (int w2 = 1; w2 < 8; ++w2) {
        double ov = swv[w2][r]; int oi = swi[w2][r];
        if (ov > bv || (ov == bv && oi < bi)) { bv = ov; bi = oi; }
      }
      if (ridx[r] >= 0) tokens[ridx[r]] = bi;
    }
  }
}

// ---------- gather z_q: exact fp32 copy + bf16 copy for the decoder
__global__ __launch_bounds__(256) void gather_kernel(
    const int* __restrict__ tokens, const float* __restrict__ cb,
    float* __restrict__ zq, unsigned short* __restrict__ zqb)
{
  int g = blockIdx.x * 256 + threadIdx.x;
  int row = g >> 4;
  int part = g & 15;
  int tok = tokens[row];
  float4 cv = ((const float4*)cb)[tok * 16 + part];
  ((float4*)zq)[g] = cv;
  ushort4 o;
  o.x = f2bf(cv.x); o.y = f2bf(cv.y); o.z = f2bf(cv.z); o.w = f2bf(cv.w);
  ((ushort4*)zqb)[g] = o;
}

extern "C" void kernel_launch(void* const* d_in, const int* in_sizes, int n_in,
                              void* d_out, int out_size, void* d_ws, size_t ws_size,
                              hipStream_t stream)
{
  const float* obs = (const float*)d_in[0];
  const float* ew1 = (const float*)d_in[1];
  const float* eb1 = (const float*)d_in[2];
  const float* ew2 = (const float*)d_in[3];
  const float* eb2 = (const float*)d_in[4];
  const float* dw1 = (const float*)d_in[5];
  const float* db1 = (const float*)d_in[6];
  const float* dw2 = (const float*)d_in[7];
  const float* db2 = (const float*)d_in[8];
  const float* cb  = (const float*)d_in[9];

  float* out_z   = (float*)d_out;                    // [65536][64]
  float* out_zq  = out_z + (size_t)ZR * EMBED;       // [65536][64]
  float* out_rec = out_z + 2 * (size_t)ZR * EMBED;   // [4096][128]

  // h 3-split (3 x 4MB) staged in the (dead-until-gather) out_zq slot
  unsigned short* h1 = (unsigned short*)out_zq;
  unsigned short* h2 = h1 + (size_t)BNR * HIDD;
  unsigned short* h3 = h2 + (size_t)BNR * HIDD;

  char* w = (char*)d_ws;
  _Float16* chi  = (_Float16*)w; w += (size_t)VOCAB * EMBED * 2;  // 512 KB
  float*    bcol = (float*)w;    w += 64 * 1024;                  // 16 KB used
  double*   bcold = (double*)w;  w += 64 * 1024;                  // 32 KB used
  float*    cbT  = (float*)w;    w += (size_t)VOCAB * EMBED * 4;  // 1 MB
  _Float16* zhi  = (_Float16*)w; w += (size_t)ZR * EMBED * 2;     // 8 MB
  _Float16* zlo  = (_Float16*)w; w += (size_t)ZR * EMBED * 2;     // 8 MB
  unsigned short* w1t1 = (unsigned short*)w; w += (size_t)HIDD * OBSD * 2;
  unsigned short* w1t2 = (unsigned short*)w; w += (size_t)HIDD * OBSD * 2;
  unsigned short* w1t3 = (unsigned short*)w; w += (size_t)HIDD * OBSD * 2;
  unsigned short* w2t1 = (unsigned short*)w; w += (size_t)ZD * HIDD * 2;
  unsigned short* w2t2 = (unsigned short*)w; w += (size_t)ZD * HIDD * 2;
  unsigned short* w2t3 = (unsigned short*)w; w += (size_t)ZD * HIDD * 2;
  unsigned short* d1t  = (unsigned short*)w; w += (size_t)HIDD * ZD * 2;
  unsigned short* d2t  = (unsigned short*)w; w += (size_t)OBSD * HIDD * 2;
  int* tokens = (int*)w;  w += (size_t)ZR * 4;
  int* rrows  = (int*)w;  w += (size_t)ZR * 4;
  int* rcnt   = (int*)w;  w += 64;
  float2* pb2 = (float2*)w; w += (size_t)NCHUNK * ZR * 8;         // 2 MB
  int*   pidx = (int*)w;    w += (size_t)NCHUNK * ZR * 4;         // 1 MB

  // overlays (dead-time disjoint):
  unsigned short* o1 = (unsigned short*)zhi;           // [prep..enc1]
  unsigned short* o2 = o1 + (size_t)BNR * OBSD;
  unsigned short* o3 = o2 + (size_t)BNR * OBSD;
  unsigned short* zqb  = (unsigned short*)zhi;         // [gather..dec1]
  unsigned short* hdec = (unsigned short*)zlo;         // [dec1..dec2]

  prep_all_kernel<<<6672, 256, 0, stream>>>(
      cb, chi, bcol, bcold, cbT,
      ew1, w1t1, w1t2, w1t3,
      ew2, w2t1, w2t2, w2t3,
      obs, o1, o2, o3,
      dw1, d1t, dw2, d2t, rcnt);

  // enc1: 3-split, tile 32x128
  gemm_lds_kernel<3, 1, true, 0><<<dim3(BNR / 32, HIDD / 128), 512, 0, stream>>>(
      o1, o2, o3, w1t1, w1t2, w1t3, eb1, BNR, HIDD, OBSD,
      h1, h2, h3, nullptr, nullptr, nullptr);
  // enc2: 3-split, tile 64x128
  gemm_lds_kernel<3, 2, false, 1><<<dim3(BNR / 64, ZD / 128), 512, 0, stream>>>(
      h1, h2, h3, w2t1, w2t2, w2t3, eb2, BNR, ZD, HIDD,
      nullptr, nullptr, nullptr, out_z, zhi, zlo);

  // dist: 64 rows/wave, 16-wave blocks, grid 256 = 1 block/CU, single round
  dist_kernel<<<dim3(ZR / 1024, NCHUNK), 1024, 0, stream>>>(
      zhi, zlo, chi, bcol, pb2, pidx);
  merge_kernel<<<ZR / 256, 256, 0, stream>>>(pb2, pidx, tokens, rcnt, rrows);
  rescue_kernel<<<512, 512, 0, stream>>>(rcnt, rrows, out_z, cbT, bcold, tokens);
  gather_kernel<<<(ZR * 16) / 256, 256, 0, stream>>>(tokens, cb, out_zq, zqb);

  // dec1: plain bf16, tile 32x128
  gemm_lds_kernel<1, 1, true, 2><<<dim3(BNR / 32, HIDD / 128), 512, 0, stream>>>(
      zqb, zqb, zqb, d1t, d1t, d1t, db1, BNR, HIDD, ZD,
      hdec, nullptr, nullptr, nullptr, nullptr, nullptr);
  // dec2: small, direct-load kernel
  dec_mfma_kernel<false, false><<<dim3(BNR / 64, OBSD / 64), 256, 0, stream>>>(
      hdec, d2t, db2, BNR, OBSD, HIDD, nullptr, out_rec);
}

// Round 13
// 212.907 us; speedup vs baseline: 3.0343x; 3.0343x over previous
//
#include <hip/hip_runtime.h>
#include <math.h>

#define VOCAB 4096
#define EMBED 64
#define OBSD  128
#define HIDD  512
#define BNR   4096        // batch rows (1024*4)
#define ZR    65536       // token rows (BNR*16)
#define ZD    1024        // 16*EMBED
#define NCHUNK 4
#define CHSZ  (VOCAB / NCHUNK)   // 1024 codes per chunk
#define TCODES 64                // codes per LDS tile
#define NTILES (CHSZ / TCODES)   // 16 tiles per chunk

// dist computes hi-only scores (zhi f16 vs chi f16): ε = Δz·c̃ + zhi·Δc,
// σ_ε ≈ 1.4e-3 scaled, pair-diff σ ≈ 2e-3. Margin 8e-3 = 4σ → expected
// unflagged flips ~0.006 chip-wide; flag rate ~1.2% → one rescue round.
#define MARGIN_SCALED 8.0e-3f

// dist LDS layout strides (halfs), padded (proven r5-r11)
#define SSTR 136
#define GSTR (8 * SSTR)          // 1088 halfs per 16-code group
#define TYPSZ (4 * GSTR)         // 4352 halfs per tile buffer (hi only)

#define RB 8                     // rescue rows per batch

typedef _Float16 half8  __attribute__((ext_vector_type(8)));
typedef _Float16 half4  __attribute__((ext_vector_type(4)));
typedef short    bf16x8 __attribute__((ext_vector_type(8)));
typedef float    f32x4  __attribute__((ext_vector_type(4)));

__device__ __forceinline__ f32x4 mfma_f16(half8 a, half8 b, f32x4 c){
  return __builtin_amdgcn_mfma_f32_16x16x32_f16(a,b,c,0,0,0);
}
__device__ __forceinline__ f32x4 mfma_bf(bf16x8 a, bf16x8 b, f32x4 c){
  return __builtin_amdgcn_mfma_f32_16x16x32_bf16(a,b,c,0,0,0);
}
__device__ __forceinline__ unsigned short f2bf(float f){
  union{float f; unsigned u;} x; x.f=f;
  unsigned u = x.u + 0x7fffu + ((x.u>>16)&1u);
  return (unsigned short)(u>>16);
}
__device__ __forceinline__ float bf2f(unsigned short h){
  union{unsigned u; float f;} x; x.u = ((unsigned)h)<<16; return x.f;
}
__device__ __forceinline__ void split3(float w, unsigned short& b1,
                                       unsigned short& b2, unsigned short& b3){
  b1 = f2bf(w); float r  = w - bf2f(b1);
  b2 = f2bf(r); float r2 = r - bf2f(b2);
  b3 = f2bf(r2);
}
__device__ __forceinline__ bf16x8 ldbf(const unsigned short* p){
  return *(const bf16x8*)(const void*)p;
}

// ---------- fused prep: cb f16 + cbT + fp64 bias + weight splits + rcnt zero
// Weight transposes iterate SOURCE-major (coalesced reads; strided writes
// absorbed by L2 write combining).
__global__ __launch_bounds__(256) void prep_all_kernel(
    const float* __restrict__ cb, _Float16* __restrict__ chi,
    float* __restrict__ bcol, double* __restrict__ bcold,
    float* __restrict__ cbT,
    const float* __restrict__ ew1, unsigned short* __restrict__ w1t1,
    unsigned short* __restrict__ w1t2, unsigned short* __restrict__ w1t3,
    const float* __restrict__ ew2, unsigned short* __restrict__ w2t1,
    unsigned short* __restrict__ w2t2, unsigned short* __restrict__ w2t3,
    const float* __restrict__ obs, unsigned short* __restrict__ o1,
    unsigned short* __restrict__ o2, unsigned short* __restrict__ o3,
    const float* __restrict__ dw1, unsigned short* __restrict__ d1t,
    const float* __restrict__ dw2, unsigned short* __restrict__ d2t,
    int* __restrict__ rcnt)
{
  const int b = blockIdx.x;
  const int t = threadIdx.x;
  if (b == 0 && t == 0) *rcnt = 0;
  if (b < 16) {
    int j = b * 256 + t;
    double s = 0.0;
    #pragma unroll 8
    for (int d = 0; d < EMBED; ++d) {
      float c = cb[j * EMBED + d];
      s += (double)c * (double)c;
      chi[j * EMBED + d] = (_Float16)(c * 4096.0f);   // pow2 scale exact
      cbT[(size_t)d * VOCAB + j] = c;                 // coalesced write
    }
    double bd = -0.5 * s * 4096.0;
    bcold[j] = bd;
    bcol[j] = (float)bd;
  } else if (b < 272) {
    // ew1 [OBSD][HIDD] -> 3-split [HIDD][OBSD]; source-major read
    int e = (b - 16) * 256 + t;          // e = k*HIDD + n
    int k = e / HIDD, n = e % HIDD;
    split3(ew1[e], w1t1[n * OBSD + k], w1t2[n * OBSD + k], w1t3[n * OBSD + k]);
  } else if (b < 2320) {
    // ew2 [HIDD][ZD] -> 3-split [ZD][HIDD]; source-major read
    int e = (b - 272) * 256 + t;         // e = k*ZD + n
    int k = e / ZD, n = e % ZD;
    split3(ew2[e], w2t1[n * HIDD + k], w2t2[n * HIDD + k], w2t3[n * HIDD + k]);
  } else if (b < 4368) {
    // obs elementwise 3-split (already coalesced)
    int e = (b - 2320) * 256 + t;
    split3(obs[e], o1[e], o2[e], o3[e]);
  } else if (b < 6416) {
    // dw1 [ZD][HIDD] -> bf16 [HIDD][ZD]; source-major read
    int e = (b - 4368) * 256 + t;        // e = k*HIDD + n
    int k = e / HIDD, n = e % HIDD;
    d1t[(size_t)n * ZD + k] = f2bf(dw1[e]);
  } else {
    // dw2 [HIDD][OBSD] -> bf16 [OBSD][HIDD]; source-major read
    int e = (b - 6416) * 256 + t;        // e = k*OBSD + n
    int k = e / OBSD, n = e % OBSD;
    d2t[(size_t)n * HIDD + k] = f2bf(dw2[e]);
  }
}

// ---------- LDS-staged GEMM template (enc1/enc2/dec1), proven r10/r11.
// OUT: 0 = relu+split3(H1..H3), 1 = Z + f16 hi (Zhi), 2 = relu+bf16(H1)
template<int NSPLIT, int MS, bool RELU, int OUT>
__global__ __launch_bounds__(512) void gemm_lds_kernel(
    const unsigned short* __restrict__ A1, const unsigned short* __restrict__ A2,
    const unsigned short* __restrict__ A3,
    const unsigned short* __restrict__ B1, const unsigned short* __restrict__ B2,
    const unsigned short* __restrict__ B3,
    const float* __restrict__ bias, int M, int N, int K,
    unsigned short* __restrict__ H1, unsigned short* __restrict__ H2,
    unsigned short* __restrict__ H3,
    float* __restrict__ Z, _Float16* __restrict__ Zhi)
{
  constexpr int BM  = MS * 32;
  constexpr int ASZ = BM * 40;          // halfs per A split
  constexpr int BSZ = 128 * 40;         // halfs per B split
  constexpr int ACH = BM * 4;           // 16B chunks per A split
  constexpr int TCH = ACH + 512;        // + B chunks (128*4)
  __shared__ unsigned short lds[NSPLIT * (ASZ + BSZ)];

  const int tid  = threadIdx.x;
  const int wave = tid >> 6;
  const int lane = tid & 63;
  const int l15  = lane & 15;
  const int lg   = lane >> 4;
  const int wm   = wave >> 2;           // 0..1
  const int wn   = wave & 3;            // 0..3
  const int m0   = blockIdx.x * BM;
  const int n0   = blockIdx.y * 128;

  const unsigned short* Aps[3] = {A1, A2, A3};
  const unsigned short* Bps[3] = {B1, B2, B3};

  // staging slots: thread handles chunks {tid, tid+512} of the (A|B) space
  size_t goff[2]; int lb[2], pst[2]; bool valid[2], isA[2];
  #pragma unroll
  for (int sl = 0; sl < 2; ++sl) {
    int c = tid + sl * 512;
    valid[sl] = c < TCH;
    bool a = c < ACH;
    isA[sl] = a;
    int cr = a ? c : (c - ACH);
    if (!valid[sl]) cr = 0;
    int row = cr >> 2, o16 = cr & 3;
    goff[sl] = (size_t)(a ? m0 + row : n0 + row) * K + o16 * 8;
    lb[sl]   = (a ? 0 : NSPLIT * ASZ) + row * 40 + o16 * 8;
    pst[sl]  = a ? ASZ : BSZ;
  }

  // prologue: stage k-step 0
  #pragma unroll
  for (int sl = 0; sl < 2; ++sl) if (valid[sl]) {
    #pragma unroll
    for (int p = 0; p < NSPLIT; ++p)
      *(bf16x8*)(void*)&lds[lb[sl] + p * pst[sl]] =
          ldbf((isA[sl] ? Aps[p] : Bps[p]) + goff[sl]);
  }
  __syncthreads();

  double accd[MS][2][4];
  f32x4  accf[MS][2];
  #pragma unroll
  for (int ms = 0; ms < MS; ++ms)
    #pragma unroll
    for (int ns = 0; ns < 2; ++ns) {
      accf[ms][ns] = (f32x4){0.f, 0.f, 0.f, 0.f};
      #pragma unroll
      for (int r = 0; r < 4; ++r) accd[ms][ns][r] = 0.0;
    }

  const int KS = K / 32;
  for (int step = 0; step < KS; ++step) {
    bf16x8 nv[NSPLIT][2];
    const bool pre = (step + 1 < KS);
    if (pre) {
      #pragma unroll
      for (int sl = 0; sl < 2; ++sl) if (valid[sl]) {
        #pragma unroll
        for (int p = 0; p < NSPLIT; ++p)
          nv[p][sl] = ldbf((isA[sl] ? Aps[p] : Bps[p]) + goff[sl]
                           + (size_t)(step + 1) * 32);
      }
    }

    bf16x8 af[NSPLIT][MS], bfr[NSPLIT][2];
    #pragma unroll
    for (int ms = 0; ms < MS; ++ms) {
      const int ar = (wm * MS * 16 + ms * 16 + l15) * 40 + lg * 8;
      #pragma unroll
      for (int p = 0; p < NSPLIT; ++p)
        af[p][ms] = *(const bf16x8*)(const void*)&lds[p * ASZ + ar];
    }
    #pragma unroll
    for (int ns = 0; ns < 2; ++ns) {
      const int br = (wn * 32 + ns * 16 + l15) * 40 + lg * 8;
      #pragma unroll
      for (int p = 0; p < NSPLIT; ++p)
        bfr[p][ns] = *(const bf16x8*)(const void*)&lds[NSPLIT * ASZ + p * BSZ + br];
    }

    #pragma unroll
    for (int ms = 0; ms < MS; ++ms)
      #pragma unroll
      for (int ns = 0; ns < 2; ++ns) {
        if constexpr (NSPLIT == 3) {
          f32x4 acc = {0.f, 0.f, 0.f, 0.f};
          // smallest terms first, dominant a1*b1 last (order == r9-r11 enc)
          acc = mfma_bf(af[0][ms], bfr[2][ns], acc);
          acc = mfma_bf(af[1][ms], bfr[1][ns], acc);
          acc = mfma_bf(af[2][ms], bfr[0][ns], acc);
          acc = mfma_bf(af[0][ms], bfr[1][ns], acc);
          acc = mfma_bf(af[1][ms], bfr[0][ns], acc);
          acc = mfma_bf(af[0][ms], bfr[0][ns], acc);
          #pragma unroll
          for (int r = 0; r < 4; ++r) accd[ms][ns][r] += (double)acc[r];
        } else {
          accf[ms][ns] = mfma_bf(af[0][ms], bfr[0][ns], accf[ms][ns]);
        }
      }

    __syncthreads();              // all waves done reading lds
    if (pre) {
      #pragma unroll
      for (int sl = 0; sl < 2; ++sl) if (valid[sl]) {
        #pragma unroll
        for (int p = 0; p < NSPLIT; ++p)
          *(bf16x8*)(void*)&lds[lb[sl] + p * pst[sl]] = nv[p][sl];
      }
    }
    __syncthreads();              // next step visible
  }

  #pragma unroll
  for (int ms = 0; ms < MS; ++ms)
    #pragma unroll
    for (int ns = 0; ns < 2; ++ns)
      #pragma unroll
      for (int r = 0; r < 4; ++r) {
        int row = m0 + wm * MS * 16 + ms * 16 + lg * 4 + r;
        int col = n0 + wn * 32 + ns * 16 + l15;
        float v = (NSPLIT == 3 ? (float)accd[ms][ns][r] : accf[ms][ns][r])
                  + bias[col];
        if constexpr (RELU) v = v > 0.f ? v : 0.f;
        size_t o = (size_t)row * N + col;
        if constexpr (OUT == 0) {
          split3(v, H1[o], H2[o], H3[o]);
        } else if constexpr (OUT == 1) {
          Z[o] = v;
          Zhi[o] = (_Float16)v;
        } else {
          H1[o] = f2bf(v);
        }
      }
}

// ---------- dec2 GEMM: plain bf16 1-pass MFMA, direct loads (small)
template<bool RELU, bool OUTBF>
__global__ __launch_bounds__(256) void dec_mfma_kernel(
    const unsigned short* __restrict__ A, const unsigned short* __restrict__ B,
    const float* __restrict__ bias, int M, int N, int K,
    unsigned short* __restrict__ Obf, float* __restrict__ Of)
{
  const int tid  = threadIdx.x;
  const int wave = tid >> 6;
  const int lane = tid & 63;
  const int l15  = lane & 15;
  const int lg   = lane >> 4;
  const int m0 = blockIdx.x * 64 + (wave >> 1) * 32;
  const int n0 = blockIdx.y * 64 + (wave & 1) * 32;

  f32x4 acc[2][2] = {};
  for (int k0 = 0; k0 < K; k0 += 32) {
    bf16x8 a[2], b[2];
    #pragma unroll
    for (int ms = 0; ms < 2; ++ms)
      a[ms] = ldbf(A + (size_t)(m0 + ms * 16 + l15) * K + k0 + lg * 8);
    #pragma unroll
    for (int ns = 0; ns < 2; ++ns)
      b[ns] = ldbf(B + (size_t)(n0 + ns * 16 + l15) * K + k0 + lg * 8);
    #pragma unroll
    for (int ms = 0; ms < 2; ++ms)
      #pragma unroll
      for (int ns = 0; ns < 2; ++ns)
        acc[ms][ns] = mfma_bf(a[ms], b[ns], acc[ms][ns]);
  }
  #pragma unroll
  for (int ms = 0; ms < 2; ++ms)
    #pragma unroll
    for (int ns = 0; ns < 2; ++ns)
      #pragma unroll
      for (int r = 0; r < 4; ++r) {
        int row = m0 + ms * 16 + lg * 4 + r;
        int col = n0 + ns * 16 + l15;
        float v = acc[ms][ns][r] + bias[col];
        if constexpr (RELU) v = v > 0.f ? v : 0.f;
        if constexpr (OUTBF) Obf[(size_t)row * N + col] = f2bf(v);
        else                 Of[(size_t)row * N + col] = v;
      }
}

// ---------- VQ distance: hi-only f16 — 2-MFMA chain (r13). r11 PMC showed
// issue saturation (MFMA 30µs + VALU 46µs busy = 87% of 87µs); VALU/score is
// irreducible, so halve MFMA by dropping the zlo term and widening the rescue
// margin to 8e-3 (4σ of the hi-only error). Shape = r11 proven: 32 rows/wave,
// 16-wave blocks, grid (128,4), single barrier/tile, LDS-staged codebook.
// NOTE: no min-waves clause & rows-32 max — r3/r12 both spilled past this.
__global__ __launch_bounds__(1024) void dist_kernel(
    const _Float16* __restrict__ zhi, const _Float16* __restrict__ chi,
    const float* __restrict__ bcol,
    float2* __restrict__ pb2, int* __restrict__ pidx)
{
  __shared__ _Float16 sh[2][TYPSZ];      // [buf][padded 64-code tile]
  __shared__ float    sbc[CHSZ];

  const int tid  = threadIdx.x;
  const int wave = tid >> 6;
  const int lane = tid & 63;
  const int l15  = lane & 15;
  const int lg   = lane >> 4;
  const int rowW = blockIdx.x * 512 + wave * 32;
  const int ch   = blockIdx.y;

  // z fragments: loop-invariant, stay in VGPRs (2 subtiles x 2 frags x 4 regs)
  half8 ah0[2], ah1[2];
  #pragma unroll
  for (int s = 0; s < 2; ++s) {
    const size_t base = (size_t)(rowW + s * 16 + l15) * EMBED + lg * 8;
    ah0[s] = *(const half8*)(zhi + base);
    ah1[s] = *(const half8*)(zhi + base + 32);
  }

  const _Float16* gsrc = chi + (size_t)ch * CHSZ * EMBED;
  const int code = tid >> 4, rem = tid & 15, sl = rem >> 1, hf = rem & 1;
  const int ld = (code >> 4) * GSTR + sl * SSTR + (code & 15) * 8 + hf * 4;
  const size_t goff = (size_t)code * EMBED + sl * 8 + hf * 4;

  sbc[tid] = bcol[ch * CHSZ + tid];

  *(half4*)(&sh[0][ld]) = *(const half4*)(gsrc + goff);
  __syncthreads();

  float best[2][4], second[2][4];
  int   bidx[2][4];
  #pragma unroll
  for (int s = 0; s < 2; ++s)
    #pragma unroll
    for (int r = 0; r < 4; ++r) {
      best[s][r] = -INFINITY; second[s][r] = -INFINITY; bidx[s][r] = 0;
    }

  for (int tile = 0; tile < NTILES; ++tile) {
    const int buf = tile & 1;
    half4 v0 = {};
    if (tile + 1 < NTILES)
      v0 = *(const half4*)(gsrc + (size_t)(tile + 1) * (TCODES * EMBED) + goff);

    const _Float16* ph = &sh[buf][0];
    #pragma unroll
    for (int grp = 0; grp < 4; ++grp) {
      const int rb = grp * GSTR + l15 * 8;
      half8 bh0 = *(const half8*)(ph + rb + lg * SSTR);
      half8 bh1 = *(const half8*)(ph + rb + (4 + lg) * SSTR);
      const int cloc = tile * TCODES + grp * 16 + l15;
      const int col  = ch * CHSZ + cloc;
      const float vb = sbc[cloc];
      const f32x4 seed = {vb, vb, vb, vb};
      #pragma unroll
      for (int s = 0; s < 2; ++s) {
        f32x4 acc = seed;
        acc = mfma_f16(ah0[s], bh0, acc);
        acc = mfma_f16(ah1[s], bh1, acc);
        #pragma unroll
        for (int r = 0; r < 4; ++r) {
          float v = acc[r];
          float sn = __builtin_amdgcn_fmed3f(second[s][r], best[s][r], v);
          bool gt = v > best[s][r];
          best[s][r] = gt ? v : best[s][r];
          bidx[s][r] = gt ? col : bidx[s][r];
          second[s][r] = sn;
        }
      }
    }
    // write next tile into the other buffer (safe: its last readers finished
    // before the previous iteration's barrier), then ONE barrier (r11).
    if (tile + 1 < NTILES)
      *(half4*)(&sh[buf ^ 1][ld]) = v0;
    __syncthreads();
  }

  #pragma unroll
  for (int m = 1; m <= 8; m <<= 1) {
    #pragma unroll
    for (int s = 0; s < 2; ++s)
      #pragma unroll
      for (int r = 0; r < 4; ++r) {
        float ob = __shfl_xor(best[s][r], m, 64);
        float os = __shfl_xor(second[s][r], m, 64);
        int   oi = __shfl_xor(bidx[s][r], m, 64);
        float mn = fminf(best[s][r], ob);
        second[s][r] = fmaxf(mn, fmaxf(second[s][r], os));
        if (ob > best[s][r]) { best[s][r] = ob; bidx[s][r] = oi; }
      }
  }

  if (l15 == 0) {
    #pragma unroll
    for (int s = 0; s < 2; ++s)
      #pragma unroll
      for (int r = 0; r < 4; ++r) {
        int row = rowW + s * 16 + lg * 4 + r;
        pb2 [(size_t)ch * ZR + row] = make_float2(best[s][r], second[s][r]);
        pidx[(size_t)ch * ZR + row] = bidx[s][r];
      }
  }
}

// ---------- merge chunk partials -> tokens + rescue list
__global__ __launch_bounds__(256) void merge_kernel(
    const float2* __restrict__ pb2, const int* __restrict__ pidx,
    int* __restrict__ tokens, int* __restrict__ rcnt, int* __restrict__ rrows)
{
  int r = blockIdx.x * 256 + threadIdx.x;
  float b = -INFINITY, s = -INFINITY;
  int bi = 0;
  #pragma unroll
  for (int c = 0; c < NCHUNK; ++c) {
    float2 p = pb2[(size_t)c * ZR + r];
    int    i = pidx[(size_t)c * ZR + r];
    if (p.x > b) { s = fmaxf(b, p.y); b = p.x; bi = i; }
    else         { s = fmaxf(s, p.x); }
  }
  tokens[r] = bi;
  if (b - s < MARGIN_SCALED) {
    int p = atomicAdd(rcnt, 1);
    if (p < ZR) rrows[p] = r;
  }
}

// ---------- rescue v2: exact fp64 rescan, batched (proven r9-r11)
__global__ __launch_bounds__(512) void rescue_kernel(
    const int* __restrict__ cnt, const int* __restrict__ rows,
    const float* __restrict__ z, const float* __restrict__ cbT,
    const double* __restrict__ bcold, int* __restrict__ tokens)
{
  __shared__ double zl[RB][EMBED];
  __shared__ int    ridx[RB];
  __shared__ double swv[8][RB];
  __shared__ int    swi[8][RB];

  int n = *cnt; if (n > ZR) n = ZR;
  int nb = (n + RB - 1) / RB;
  const int tid = threadIdx.x;

  for (int batch = blockIdx.x; batch < nb; batch += gridDim.x) {
    __syncthreads();
    if (tid < RB) {
      int e = batch * RB + tid;
      ridx[tid] = (e < n) ? rows[e] : -1;
    }
    __syncthreads();
    {
      int r = tid >> 6, k = tid & 63;
      int rr = ridx[r];
      zl[r][k] = (rr >= 0) ? (double)z[(size_t)rr * EMBED + k] : 0.0;
    }
    __syncthreads();

    double best[RB]; int bidx[RB];
    #pragma unroll
    for (int r = 0; r < RB; ++r) { best[r] = -1.0e300; bidx[r] = 0; }

    for (int c = 0; c < VOCAB / 512; ++c) {
      const int j = c * 512 + tid;
      double acc[RB] = {};
      #pragma unroll 16
      for (int k = 0; k < EMBED; ++k) {
        double cd = (double)cbT[(size_t)k * VOCAB + j];
        #pragma unroll
        for (int r = 0; r < RB; ++r)
          acc[r] = fma(cd, zl[r][k], acc[r]);
      }
      const double bc = bcold[j];
      #pragma unroll
      for (int r = 0; r < RB; ++r) {
        double s = 4096.0 * acc[r] + bc;
        if (s > best[r]) { best[r] = s; bidx[r] = j; }
      }
    }

    #pragma unroll
    for (int m = 1; m < 64; m <<= 1) {
      #pragma unroll
      for (int r = 0; r < RB; ++r) {
        double ov = __shfl_xor(best[r], m, 64);
        int    oi = __shfl_xor(bidx[r], m, 64);
        if (ov > best[r] || (ov == best[r] && oi < bidx[r])) {
          best[r] = ov; bidx[r] = oi;
        }
      }
    }
    const int wv = tid >> 6, ln = tid & 63;
    if (ln == 0)
      #pragma unroll
      for (int r = 0; r < RB; ++r) { swv[wv][r] = best[r]; swi[wv][r] = bidx[r]; }
    __syncthreads();
    if (tid < RB) {
      int r = tid;
      double bv = swv[0][r]; int bi = swi[0][r];
      #pragma unroll
      for (int w2 = 1; w2 < 8; ++w2) {
        double ov = swv[w2][r]; int oi = swi[w2][r];
        if (ov > bv || (ov == bv && oi < bi)) { bv = ov; bi = oi; }
      }
      if (ridx[r] >= 0) tokens[ridx[r]] = bi;
    }
  }
}

// ---------- gather z_q: exact fp32 copy + bf16 copy for the decoder
__global__ __launch_bounds__(256) void gather_kernel(
    const int* __restrict__ tokens, const float* __restrict__ cb,
    float* __restrict__ zq, unsigned short* __restrict__ zqb)
{
  int g = blockIdx.x * 256 + threadIdx.x;
  int row = g >> 4;
  int part = g & 15;
  int tok = tokens[row];
  float4 cv = ((const float4*)cb)[tok * 16 + part];
  ((float4*)zq)[g] = cv;
  ushort4 o;
  o.x = f2bf(cv.x); o.y = f2bf(cv.y); o.z = f2bf(cv.z); o.w = f2bf(cv.w);
  ((ushort4*)zqb)[g] = o;
}

extern "C" void kernel_launch(void* const* d_in, const int* in_sizes, int n_in,
                              void* d_out, int out_size, void* d_ws, size_t ws_size,
                              hipStream_t stream)
{
  const float* obs = (const float*)d_in[0];
  const float* ew1 = (const float*)d_in[1];
  const float* eb1 = (const float*)d_in[2];
  const float* ew2 = (const float*)d_in[3];
  const float* eb2 = (const float*)d_in[4];
  const float* dw1 = (const float*)d_in[5];
  const float* db1 = (const float*)d_in[6];
  const float* dw2 = (const float*)d_in[7];
  const float* db2 = (const float*)d_in[8];
  const float* cb  = (const float*)d_in[9];

  float* out_z   = (float*)d_out;                    // [65536][64]
  float* out_zq  = out_z + (size_t)ZR * EMBED;       // [65536][64]
  float* out_rec = out_z + 2 * (size_t)ZR * EMBED;   // [4096][128]

  // h 3-split (3 x 4MB) staged in the (dead-until-gather) out_zq slot
  unsigned short* h1 = (unsigned short*)out_zq;
  unsigned short* h2 = h1 + (size_t)BNR * HIDD;
  unsigned short* h3 = h2 + (size_t)BNR * HIDD;

  char* w = (char*)d_ws;
  _Float16* chi  = (_Float16*)w; w += (size_t)VOCAB * EMBED * 2;  // 512 KB
  float*    bcol = (float*)w;    w += 64 * 1024;                  // 16 KB used
  double*   bcold = (double*)w;  w += 64 * 1024;                  // 32 KB used
  float*    cbT  = (float*)w;    w += (size_t)VOCAB * EMBED * 4;  // 1 MB
  _Float16* zhi  = (_Float16*)w; w += (size_t)ZR * EMBED * 2;     // 8 MB
  char*     spare = w;           w += (size_t)ZR * EMBED * 2;     // 8 MB (hdec)
  unsigned short* w1t1 = (unsigned short*)w; w += (size_t)HIDD * OBSD * 2;
  unsigned short* w1t2 = (unsigned short*)w; w += (size_t)HIDD * OBSD * 2;
  unsigned short* w1t3 = (unsigned short*)w; w += (size_t)HIDD * OBSD * 2;
  unsigned short* w2t1 = (unsigned short*)w; w += (size_t)ZD * HIDD * 2;
  unsigned short* w2t2 = (unsigned short*)w; w += (size_t)ZD * HIDD * 2;
  unsigned short* w2t3 = (unsigned short*)w; w += (size_t)ZD * HIDD * 2;
  unsigned short* d1t  = (unsigned short*)w; w += (size_t)HIDD * ZD * 2;
  unsigned short* d2t  = (unsigned short*)w; w += (size_t)OBSD * HIDD * 2;
  int* tokens = (int*)w;  w += (size_t)ZR * 4;
  int* rrows  = (int*)w;  w += (size_t)ZR * 4;
  int* rcnt   = (int*)w;  w += 64;
  float2* pb2 = (float2*)w; w += (size_t)NCHUNK * ZR * 8;         // 2 MB
  int*   pidx = (int*)w;    w += (size_t)NCHUNK * ZR * 4;         // 1 MB

  // overlays (dead-time disjoint):
  unsigned short* o1 = (unsigned short*)zhi;           // [prep..enc1]
  unsigned short* o2 = o1 + (size_t)BNR * OBSD;
  unsigned short* o3 = o2 + (size_t)BNR * OBSD;
  unsigned short* zqb  = (unsigned short*)zhi;         // [gather..dec1]
  unsigned short* hdec = (unsigned short*)spare;       // [dec1..dec2]

  prep_all_kernel<<<6672, 256, 0, stream>>>(
      cb, chi, bcol, bcold, cbT,
      ew1, w1t1, w1t2, w1t3,
      ew2, w2t1, w2t2, w2t3,
      obs, o1, o2, o3,
      dw1, d1t, dw2, d2t, rcnt);

  // enc1: 3-split, tile 32x128
  gemm_lds_kernel<3, 1, true, 0><<<dim3(BNR / 32, HIDD / 128), 512, 0, stream>>>(
      o1, o2, o3, w1t1, w1t2, w1t3, eb1, BNR, HIDD, OBSD,
      h1, h2, h3, nullptr, nullptr);
  // enc2: 3-split, tile 64x128
  gemm_lds_kernel<3, 2, false, 1><<<dim3(BNR / 64, ZD / 128), 512, 0, stream>>>(
      h1, h2, h3, w2t1, w2t2, w2t3, eb2, BNR, ZD, HIDD,
      nullptr, nullptr, nullptr, out_z, zhi);

  // dist: 32 rows/wave (r11 shape), hi-only 2-MFMA chain
  dist_kernel<<<dim3(ZR / 512, NCHUNK), 1024, 0, stream>>>(
      zhi, chi, bcol, pb2, pidx);
  merge_kernel<<<ZR / 256, 256, 0, stream>>>(pb2, pidx, tokens, rcnt, rrows);
  rescue_kernel<<<512, 512, 0, stream>>>(rcnt, rrows, out_z, cbT, bcold, tokens);
  gather_kernel<<<(ZR * 16) / 256, 256, 0, stream>>>(tokens, cb, out_zq, zqb);

  // dec1: plain bf16, tile 32x128
  gemm_lds_kernel<1, 1, true, 2><<<dim3(BNR / 32, HIDD / 128), 512, 0, stream>>>(
      zqb, zqb, zqb, d1t, d1t, d1t, db1, BNR, HIDD, ZD,
      hdec, nullptr, nullptr, nullptr, nullptr);
  // dec2: small, direct-load kernel
  dec_mfma_kernel<false, false><<<dim3(BNR / 64, OBSD / 64), 256, 0, stream>>>(
      hdec, d2t, db2, BNR, OBSD, HIDD, nullptr, out_rec);
}

// Round 14
// 203.351 us; speedup vs baseline: 3.1769x; 1.0470x over previous
//
#include <hip/hip_runtime.h>
#include <math.h>

#define VOCAB 4096
#define EMBED 64
#define OBSD  128
#define HIDD  512
#define BNR   4096        // batch rows (1024*4)
#define ZR    65536       // token rows (BNR*16)
#define ZD    1024        // 16*EMBED
#define NCHUNK 4
#define CHSZ  (VOCAB / NCHUNK)   // 1024 codes per chunk
#define TCODES 64                // codes per LDS tile
#define NTILES (CHSZ / TCODES)   // 16 tiles per chunk

// dist computes hi-only scores (zhi f16 vs chi f16): ε = Δz·c̃ + zhi·Δc,
// σ_ε ≈ 1.4e-3 scaled, pair-diff σ ≈ 2e-3. Margin 8e-3 = 4σ → expected
// unflagged flips ~0.006 chip-wide; flag rate ~1.2% → one rescue round.
// Proven r13.
#define MARGIN_SCALED 8.0e-3f

// dist LDS layout strides (halfs), padded (proven r5-r13)
#define SSTR 136
#define GSTR (8 * SSTR)          // 1088 halfs per 16-code group
#define TYPSZ (4 * GSTR)         // 4352 halfs per tile buffer (hi only)

#define RB 8                     // rescue rows per batch

typedef _Float16 half8  __attribute__((ext_vector_type(8)));
typedef _Float16 half4  __attribute__((ext_vector_type(4)));
typedef short    bf16x8 __attribute__((ext_vector_type(8)));
typedef float    f32x4  __attribute__((ext_vector_type(4)));

__device__ __forceinline__ f32x4 mfma_f16(half8 a, half8 b, f32x4 c){
  return __builtin_amdgcn_mfma_f32_16x16x32_f16(a,b,c,0,0,0);
}
__device__ __forceinline__ f32x4 mfma_bf(bf16x8 a, bf16x8 b, f32x4 c){
  return __builtin_amdgcn_mfma_f32_16x16x32_bf16(a,b,c,0,0,0);
}
__device__ __forceinline__ unsigned short f2bf(float f){
  union{float f; unsigned u;} x; x.f=f;
  unsigned u = x.u + 0x7fffu + ((x.u>>16)&1u);
  return (unsigned short)(u>>16);
}
__device__ __forceinline__ float bf2f(unsigned short h){
  union{unsigned u; float f;} x; x.u = ((unsigned)h)<<16; return x.f;
}
__device__ __forceinline__ void split3(float w, unsigned short& b1,
                                       unsigned short& b2, unsigned short& b3){
  b1 = f2bf(w); float r  = w - bf2f(b1);
  b2 = f2bf(r); float r2 = r - bf2f(b2);
  b3 = f2bf(r2);
}
__device__ __forceinline__ bf16x8 ldbf(const unsigned short* p){
  return *(const bf16x8*)(const void*)p;
}

// ---------- LDS-tiled 32x32 transpose helper (coalesced read AND write).
// r13 post-mortem: r12's source-major transposes wrote 2B at 1-2KB stride
// (~32x write amplification, ~250MB hidden traffic). lds[32][33]: +1 pad
// makes the column read conflict-free.
__device__ __forceinline__ void ttile(
    float (*lds)[33], const float* __restrict__ src, int R, int C,
    int ti, int tj, int t, unsigned short* __restrict__ q1,
    unsigned short* __restrict__ q2, unsigned short* __restrict__ q3,
    bool three)
{
  const int r = t >> 5, c = t & 31;
  #pragma unroll
  for (int q = 0; q < 4; ++q)
    lds[r + 8 * q][c] = src[(size_t)(ti * 32 + r + 8 * q) * C + tj * 32 + c];
  __syncthreads();
  #pragma unroll
  for (int q = 0; q < 4; ++q) {
    const int wr = r + 8 * q;
    const float v = lds[c][wr];
    const size_t o = (size_t)(tj * 32 + wr) * R + ti * 32 + c;
    if (three) {
      unsigned short b1, b2, b3;
      split3(v, b1, b2, b3);
      q1[o] = b1; q2[o] = b2; q3[o] = b3;
    } else {
      q1[o] = f2bf(v);
    }
  }
}

// ---------- fused prep v3: cb + obs split + LDS-tiled weight transposes
__global__ __launch_bounds__(256) void prep_all_kernel(
    const float* __restrict__ cb, _Float16* __restrict__ chi,
    float* __restrict__ bcol, double* __restrict__ bcold,
    float* __restrict__ cbT,
    const float* __restrict__ ew1, unsigned short* __restrict__ w1t1,
    unsigned short* __restrict__ w1t2, unsigned short* __restrict__ w1t3,
    const float* __restrict__ ew2, unsigned short* __restrict__ w2t1,
    unsigned short* __restrict__ w2t2, unsigned short* __restrict__ w2t3,
    const float* __restrict__ obs, unsigned short* __restrict__ o1,
    unsigned short* __restrict__ o2, unsigned short* __restrict__ o3,
    const float* __restrict__ dw1, unsigned short* __restrict__ d1t,
    const float* __restrict__ dw2, unsigned short* __restrict__ d2t,
    int* __restrict__ rcnt)
{
  __shared__ float tl[32][33];
  const int b = blockIdx.x;
  const int t = threadIdx.x;
  if (b == 0 && t == 0) *rcnt = 0;
  if (b < 16) {
    // codebook: f16 (x4096) + fp32 transpose + -0.5||c||^2*4096 (f32+f64)
    int j = b * 256 + t;
    double s = 0.0;
    #pragma unroll 8
    for (int d = 0; d < EMBED; ++d) {
      float c = cb[j * EMBED + d];
      s += (double)c * (double)c;
      chi[j * EMBED + d] = (_Float16)(c * 4096.0f);   // pow2 scale exact
      cbT[(size_t)d * VOCAB + j] = c;                 // coalesced write
    }
    double bd = -0.5 * s * 4096.0;
    bcold[j] = bd;
    bcol[j] = (float)bd;
  } else if (b < 2064) {
    // obs elementwise 3-split (coalesced both sides)
    int e = (b - 16) * 256 + t;
    split3(obs[e], o1[e], o2[e], o3[e]);
  } else if (b < 2128) {
    // ew1 [128][512] -> w1t [512][128], split3
    int tt = b - 2064;
    ttile(tl, ew1, OBSD, HIDD, tt >> 4, tt & 15, t, w1t1, w1t2, w1t3, true);
  } else if (b < 2640) {
    // ew2 [512][1024] -> w2t [1024][512], split3
    int tt = b - 2128;
    ttile(tl, ew2, HIDD, ZD, tt >> 5, tt & 31, t, w2t1, w2t2, w2t3, true);
  } else if (b < 3152) {
    // dw1 [1024][512] -> d1t [512][1024], bf16
    int tt = b - 2640;
    ttile(tl, dw1, ZD, HIDD, tt >> 4, tt & 15, t, d1t, nullptr, nullptr, false);
  } else {
    // dw2 [512][128] -> d2t [128][512], bf16
    int tt = b - 3152;
    ttile(tl, dw2, HIDD, OBSD, tt >> 2, tt & 3, t, d2t, nullptr, nullptr, false);
  }
}

// ---------- LDS-staged GEMM template (enc1/enc2/dec1), proven r10-r13.
// r14: fp64 drain REMOVED — 6-MFMA chain accumulates through a persistent
// f32 C-in (extra error ~2e-9 abs on z; margin/rescue machinery absorbs it).
// OUT: 0 = relu+split3(H1..H3), 1 = Z + f16 hi (Zhi), 2 = relu+bf16(H1)
template<int NSPLIT, int MS, bool RELU, int OUT>
__global__ __launch_bounds__(512) void gemm_lds_kernel(
    const unsigned short* __restrict__ A1, const unsigned short* __restrict__ A2,
    const unsigned short* __restrict__ A3,
    const unsigned short* __restrict__ B1, const unsigned short* __restrict__ B2,
    const unsigned short* __restrict__ B3,
    const float* __restrict__ bias, int M, int N, int K,
    unsigned short* __restrict__ H1, unsigned short* __restrict__ H2,
    unsigned short* __restrict__ H3,
    float* __restrict__ Z, _Float16* __restrict__ Zhi)
{
  constexpr int BM  = MS * 32;
  constexpr int ASZ = BM * 40;          // halfs per A split
  constexpr int BSZ = 128 * 40;         // halfs per B split
  constexpr int ACH = BM * 4;           // 16B chunks per A split
  constexpr int TCH = ACH + 512;        // + B chunks (128*4)
  __shared__ unsigned short lds[NSPLIT * (ASZ + BSZ)];

  const int tid  = threadIdx.x;
  const int wave = tid >> 6;
  const int lane = tid & 63;
  const int l15  = lane & 15;
  const int lg   = lane >> 4;
  const int wm   = wave >> 2;           // 0..1
  const int wn   = wave & 3;            // 0..3
  const int m0   = blockIdx.x * BM;
  const int n0   = blockIdx.y * 128;

  const unsigned short* Aps[3] = {A1, A2, A3};
  const unsigned short* Bps[3] = {B1, B2, B3};

  // staging slots: thread handles chunks {tid, tid+512} of the (A|B) space
  size_t goff[2]; int lb[2], pst[2]; bool valid[2], isA[2];
  #pragma unroll
  for (int sl = 0; sl < 2; ++sl) {
    int c = tid + sl * 512;
    valid[sl] = c < TCH;
    bool a = c < ACH;
    isA[sl] = a;
    int cr = a ? c : (c - ACH);
    if (!valid[sl]) cr = 0;
    int row = cr >> 2, o16 = cr & 3;
    goff[sl] = (size_t)(a ? m0 + row : n0 + row) * K + o16 * 8;
    lb[sl]   = (a ? 0 : NSPLIT * ASZ) + row * 40 + o16 * 8;
    pst[sl]  = a ? ASZ : BSZ;
  }

  // prologue: stage k-step 0
  #pragma unroll
  for (int sl = 0; sl < 2; ++sl) if (valid[sl]) {
    #pragma unroll
    for (int p = 0; p < NSPLIT; ++p)
      *(bf16x8*)(void*)&lds[lb[sl] + p * pst[sl]] =
          ldbf((isA[sl] ? Aps[p] : Bps[p]) + goff[sl]);
  }
  __syncthreads();

  f32x4 accf[MS][2];
  #pragma unroll
  for (int ms = 0; ms < MS; ++ms)
    #pragma unroll
    for (int ns = 0; ns < 2; ++ns)
      accf[ms][ns] = (f32x4){0.f, 0.f, 0.f, 0.f};

  const int KS = K / 32;
  for (int step = 0; step < KS; ++step) {
    bf16x8 nv[NSPLIT][2];
    const bool pre = (step + 1 < KS);
    if (pre) {
      #pragma unroll
      for (int sl = 0; sl < 2; ++sl) if (valid[sl]) {
        #pragma unroll
        for (int p = 0; p < NSPLIT; ++p)
          nv[p][sl] = ldbf((isA[sl] ? Aps[p] : Bps[p]) + goff[sl]
                           + (size_t)(step + 1) * 32);
      }
    }

    bf16x8 af[NSPLIT][MS], bfr[NSPLIT][2];
    #pragma unroll
    for (int ms = 0; ms < MS; ++ms) {
      const int ar = (wm * MS * 16 + ms * 16 + l15) * 40 + lg * 8;
      #pragma unroll
      for (int p = 0; p < NSPLIT; ++p)
        af[p][ms] = *(const bf16x8*)(const void*)&lds[p * ASZ + ar];
    }
    #pragma unroll
    for (int ns = 0; ns < 2; ++ns) {
      const int br = (wn * 32 + ns * 16 + l15) * 40 + lg * 8;
      #pragma unroll
      for (int p = 0; p < NSPLIT; ++p)
        bfr[p][ns] = *(const bf16x8*)(const void*)&lds[NSPLIT * ASZ + p * BSZ + br];
    }

    #pragma unroll
    for (int ms = 0; ms < MS; ++ms)
      #pragma unroll
      for (int ns = 0; ns < 2; ++ns) {
        if constexpr (NSPLIT == 3) {
          f32x4 acc = accf[ms][ns];
          // smallest terms first, dominant a1*b1 last
          acc = mfma_bf(af[0][ms], bfr[2][ns], acc);
          acc = mfma_bf(af[1][ms], bfr[1][ns], acc);
          acc = mfma_bf(af[2][ms], bfr[0][ns], acc);
          acc = mfma_bf(af[0][ms], bfr[1][ns], acc);
          acc = mfma_bf(af[1][ms], bfr[0][ns], acc);
          acc = mfma_bf(af[0][ms], bfr[0][ns], acc);
          accf[ms][ns] = acc;
        } else {
          accf[ms][ns] = mfma_bf(af[0][ms], bfr[0][ns], accf[ms][ns]);
        }
      }

    __syncthreads();              // all waves done reading lds
    if (pre) {
      #pragma unroll
      for (int sl = 0; sl < 2; ++sl) if (valid[sl]) {
        #pragma unroll
        for (int p = 0; p < NSPLIT; ++p)
          *(bf16x8*)(void*)&lds[lb[sl] + p * pst[sl]] = nv[p][sl];
      }
    }
    __syncthreads();              // next step visible
  }

  #pragma unroll
  for (int ms = 0; ms < MS; ++ms)
    #pragma unroll
    for (int ns = 0; ns < 2; ++ns)
      #pragma unroll
      for (int r = 0; r < 4; ++r) {
        int row = m0 + wm * MS * 16 + ms * 16 + lg * 4 + r;
        int col = n0 + wn * 32 + ns * 16 + l15;
        float v = accf[ms][ns][r] + bias[col];
        if constexpr (RELU) v = v > 0.f ? v : 0.f;
        size_t o = (size_t)row * N + col;
        if constexpr (OUT == 0) {
          split3(v, H1[o], H2[o], H3[o]);
        } else if constexpr (OUT == 1) {
          Z[o] = v;
          Zhi[o] = (_Float16)v;
        } else {
          H1[o] = f2bf(v);
        }
      }
}

// ---------- dec2 GEMM: plain bf16 1-pass MFMA, direct loads (small)
template<bool RELU, bool OUTBF>
__global__ __launch_bounds__(256) void dec_mfma_kernel(
    const unsigned short* __restrict__ A, const unsigned short* __restrict__ B,
    const float* __restrict__ bias, int M, int N, int K,
    unsigned short* __restrict__ Obf, float* __restrict__ Of)
{
  const int tid  = threadIdx.x;
  const int wave = tid >> 6;
  const int lane = tid & 63;
  const int l15  = lane & 15;
  const int lg   = lane >> 4;
  const int m0 = blockIdx.x * 64 + (wave >> 1) * 32;
  const int n0 = blockIdx.y * 64 + (wave & 1) * 32;

  f32x4 acc[2][2] = {};
  for (int k0 = 0; k0 < K; k0 += 32) {
    bf16x8 a[2], b[2];
    #pragma unroll
    for (int ms = 0; ms < 2; ++ms)
      a[ms] = ldbf(A + (size_t)(m0 + ms * 16 + l15) * K + k0 + lg * 8);
    #pragma unroll
    for (int ns = 0; ns < 2; ++ns)
      b[ns] = ldbf(B + (size_t)(n0 + ns * 16 + l15) * K + k0 + lg * 8);
    #pragma unroll
    for (int ms = 0; ms < 2; ++ms)
      #pragma unroll
      for (int ns = 0; ns < 2; ++ns)
        acc[ms][ns] = mfma_bf(a[ms], b[ns], acc[ms][ns]);
  }
  #pragma unroll
  for (int ms = 0; ms < 2; ++ms)
    #pragma unroll
    for (int ns = 0; ns < 2; ++ns)
      #pragma unroll
      for (int r = 0; r < 4; ++r) {
        int row = m0 + ms * 16 + lg * 4 + r;
        int col = n0 + ns * 16 + l15;
        float v = acc[ms][ns][r] + bias[col];
        if constexpr (RELU) v = v > 0.f ? v : 0.f;
        if constexpr (OUTBF) Obf[(size_t)row * N + col] = f2bf(v);
        else                 Of[(size_t)row * N + col] = v;
      }
}

// ---------- VQ distance: hi-only f16 — 2-MFMA chain (proven r13).
// 32 rows/wave, 16-wave blocks, grid (128,4), single barrier/tile.
// NOTE: no min-waves clause & rows-32 max — r3/r12 both spilled past this.
__global__ __launch_bounds__(1024) void dist_kernel(
    const _Float16* __restrict__ zhi, const _Float16* __restrict__ chi,
    const float* __restrict__ bcol,
    float2* __restrict__ pb2, int* __restrict__ pidx)
{
  __shared__ _Float16 sh[2][TYPSZ];      // [buf][padded 64-code tile]
  __shared__ float    sbc[CHSZ];

  const int tid  = threadIdx.x;
  const int wave = tid >> 6;
  const int lane = tid & 63;
  const int l15  = lane & 15;
  const int lg   = lane >> 4;
  const int rowW = blockIdx.x * 512 + wave * 32;
  const int ch   = blockIdx.y;

  half8 ah0[2], ah1[2];
  #pragma unroll
  for (int s = 0; s < 2; ++s) {
    const size_t base = (size_t)(rowW + s * 16 + l15) * EMBED + lg * 8;
    ah0[s] = *(const half8*)(zhi + base);
    ah1[s] = *(const half8*)(zhi + base + 32);
  }

  const _Float16* gsrc = chi + (size_t)ch * CHSZ * EMBED;
  const int code = tid >> 4, rem = tid & 15, sl = rem >> 1, hf = rem & 1;
  const int ld = (code >> 4) * GSTR + sl * SSTR + (code & 15) * 8 + hf * 4;
  const size_t goff = (size_t)code * EMBED + sl * 8 + hf * 4;

  sbc[tid] = bcol[ch * CHSZ + tid];

  *(half4*)(&sh[0][ld]) = *(const half4*)(gsrc + goff);
  __syncthreads();

  float best[2][4], second[2][4];
  int   bidx[2][4];
  #pragma unroll
  for (int s = 0; s < 2; ++s)
    #pragma unroll
    for (int r = 0; r < 4; ++r) {
      best[s][r] = -INFINITY; second[s][r] = -INFINITY; bidx[s][r] = 0;
    }

  for (int tile = 0; tile < NTILES; ++tile) {
    const int buf = tile & 1;
    half4 v0 = {};
    if (tile + 1 < NTILES)
      v0 = *(const half4*)(gsrc + (size_t)(tile + 1) * (TCODES * EMBED) + goff);

    const _Float16* ph = &sh[buf][0];
    #pragma unroll
    for (int grp = 0; grp < 4; ++grp) {
      const int rb = grp * GSTR + l15 * 8;
      half8 bh0 = *(const half8*)(ph + rb + lg * SSTR);
      half8 bh1 = *(const half8*)(ph + rb + (4 + lg) * SSTR);
      const int cloc = tile * TCODES + grp * 16 + l15;
      const int col  = ch * CHSZ + cloc;
      const float vb = sbc[cloc];
      const f32x4 seed = {vb, vb, vb, vb};
      #pragma unroll
      for (int s = 0; s < 2; ++s) {
        f32x4 acc = seed;
        acc = mfma_f16(ah0[s], bh0, acc);
        acc = mfma_f16(ah1[s], bh1, acc);
        #pragma unroll
        for (int r = 0; r < 4; ++r) {
          float v = acc[r];
          float sn = __builtin_amdgcn_fmed3f(second[s][r], best[s][r], v);
          bool gt = v > best[s][r];
          best[s][r] = gt ? v : best[s][r];
          bidx[s][r] = gt ? col : bidx[s][r];
          second[s][r] = sn;
        }
      }
    }
    if (tile + 1 < NTILES)
      *(half4*)(&sh[buf ^ 1][ld]) = v0;
    __syncthreads();
  }

  #pragma unroll
  for (int m = 1; m <= 8; m <<= 1) {
    #pragma unroll
    for (int s = 0; s < 2; ++s)
      #pragma unroll
      for (int r = 0; r < 4; ++r) {
        float ob = __shfl_xor(best[s][r], m, 64);
        float os = __shfl_xor(second[s][r], m, 64);
        int   oi = __shfl_xor(bidx[s][r], m, 64);
        float mn = fminf(best[s][r], ob);
        second[s][r] = fmaxf(mn, fmaxf(second[s][r], os));
        if (ob > best[s][r]) { best[s][r] = ob; bidx[s][r] = oi; }
      }
  }

  if (l15 == 0) {
    #pragma unroll
    for (int s = 0; s < 2; ++s)
      #pragma unroll
      for (int r = 0; r < 4; ++r) {
        int row = rowW + s * 16 + lg * 4 + r;
        pb2 [(size_t)ch * ZR + row] = make_float2(best[s][r], second[s][r]);
        pidx[(size_t)ch * ZR + row] = bidx[s][r];
      }
  }
}

// ---------- merge chunk partials -> tokens + rescue list
__global__ __launch_bounds__(256) void merge_kernel(
    const float2* __restrict__ pb2, const int* __restrict__ pidx,
    int* __restrict__ tokens, int* __restrict__ rcnt, int* __restrict__ rrows)
{
  int r = blockIdx.x * 256 + threadIdx.x;
  float b = -INFINITY, s = -INFINITY;
  int bi = 0;
  #pragma unroll
  for (int c = 0; c < NCHUNK; ++c) {
    float2 p = pb2[(size_t)c * ZR + r];
    int    i = pidx[(size_t)c * ZR + r];
    if (p.x > b) { s = fmaxf(b, p.y); b = p.x; bi = i; }
    else         { s = fmaxf(s, p.x); }
  }
  tokens[r] = bi;
  if (b - s < MARGIN_SCALED) {
    int p = atomicAdd(rcnt, 1);
    if (p < ZR) rrows[p] = r;
  }
}

// ---------- rescue v2: exact fp64 rescan, batched (proven r9-r13)
__global__ __launch_bounds__(512) void rescue_kernel(
    const int* __restrict__ cnt, const int* __restrict__ rows,
    const float* __restrict__ z, const float* __restrict__ cbT,
    const double* __restrict__ bcold, int* __restrict__ tokens)
{
  __shared__ double zl[RB][EMBED];
  __shared__ int    ridx[RB];
  __shared__ double swv[8][RB];
  __shared__ int    swi[8][RB];

  int n = *cnt; if (n > ZR) n = ZR;
  int nb = (n + RB - 1) / RB;
  const int tid = threadIdx.x;

  for (int batch = blockIdx.x; batch < nb; batch += gridDim.x) {
    __syncthreads();
    if (tid < RB) {
      int e = batch * RB + tid;
      ridx[tid] = (e < n) ? rows[e] : -1;
    }
    __syncthreads();
    {
      int r = tid >> 6, k = tid & 63;
      int rr = ridx[r];
      zl[r][k] = (rr >= 0) ? (double)z[(size_t)rr * EMBED + k] : 0.0;
    }
    __syncthreads();

    double best[RB]; int bidx[RB];
    #pragma unroll
    for (int r = 0; r < RB; ++r) { best[r] = -1.0e300; bidx[r] = 0; }

    for (int c = 0; c < VOCAB / 512; ++c) {
      const int j = c * 512 + tid;
      double acc[RB] = {};
      #pragma unroll 16
      for (int k = 0; k < EMBED; ++k) {
        double cd = (double)cbT[(size_t)k * VOCAB + j];
        #pragma unroll
        for (int r = 0; r < RB; ++r)
          acc[r] = fma(cd, zl[r][k], acc[r]);
      }
      const double bc = bcold[j];
      #pragma unroll
      for (int r = 0; r < RB; ++r) {
        double s = 4096.0 * acc[r] + bc;
        if (s > best[r]) { best[r] = s; bidx[r] = j; }
      }
    }

    #pragma unroll
    for (int m = 1; m < 64; m <<= 1) {
      #pragma unroll
      for (int r = 0; r < RB; ++r) {
        double ov = __shfl_xor(best[r], m, 64);
        int    oi = __shfl_xor(bidx[r], m, 64);
        if (ov > best[r] || (ov == best[r] && oi < bidx[r])) {
          best[r] = ov; bidx[r] = oi;
        }
      }
    }
    const int wv = tid >> 6, ln = tid & 63;
    if (ln == 0)
      #pragma unroll
      for (int r = 0; r < RB; ++r) { swv[wv][r] = best[r]; swi[wv][r] = bidx[r]; }
    __syncthreads();
    if (tid < RB) {
      int r = tid;
      double bv = swv[0][r]; int bi = swi[0][r];
      #pragma unroll
      for (int w2 = 1; w2 < 8; ++w2) {
        double ov = swv[w2][r]; int oi = swi[w2][r];
        if (ov > bv || (ov == bv && oi < bi)) { bv = ov; bi = oi; }
      }
      if (ridx[r] >= 0) tokens[ridx[r]] = bi;
    }
  }
}

// ---------- gather z_q: exact fp32 copy + bf16 copy for the decoder
__global__ __launch_bounds__(256) void gather_kernel(
    const int* __restrict__ tokens, const float* __restrict__ cb,
    float* __restrict__ zq, unsigned short* __restrict__ zqb)
{
  int g = blockIdx.x * 256 + threadIdx.x;
  int row = g >> 4;
  int part = g & 15;
  int tok = tokens[row];
  float4 cv = ((const float4*)cb)[tok * 16 + part];
  ((float4*)zq)[g] = cv;
  ushort4 o;
  o.x = f2bf(cv.x); o.y = f2bf(cv.y); o.z = f2bf(cv.z); o.w = f2bf(cv.w);
  ((ushort4*)zqb)[g] = o;
}

extern "C" void kernel_launch(void* const* d_in, const int* in_sizes, int n_in,
                              void* d_out, int out_size, void* d_ws, size_t ws_size,
                              hipStream_t stream)
{
  const float* obs = (const float*)d_in[0];
  const float* ew1 = (const float*)d_in[1];
  const float* eb1 = (const float*)d_in[2];
  const float* ew2 = (const float*)d_in[3];
  const float* eb2 = (const float*)d_in[4];
  const float* dw1 = (const float*)d_in[5];
  const float* db1 = (const float*)d_in[6];
  const float* dw2 = (const float*)d_in[7];
  const float* db2 = (const float*)d_in[8];
  const float* cb  = (const float*)d_in[9];

  float* out_z   = (float*)d_out;                    // [65536][64]
  float* out_zq  = out_z + (size_t)ZR * EMBED;       // [65536][64]
  float* out_rec = out_z + 2 * (size_t)ZR * EMBED;   // [4096][128]

  // h 3-split (3 x 4MB) staged in the (dead-until-gather) out_zq slot
  unsigned short* h1 = (unsigned short*)out_zq;
  unsigned short* h2 = h1 + (size_t)BNR * HIDD;
  unsigned short* h3 = h2 + (size_t)BNR * HIDD;

  char* w = (char*)d_ws;
  _Float16* chi  = (_Float16*)w; w += (size_t)VOCAB * EMBED * 2;  // 512 KB
  float*    bcol = (float*)w;    w += 64 * 1024;                  // 16 KB used
  double*   bcold = (double*)w;  w += 64 * 1024;                  // 32 KB used
  float*    cbT  = (float*)w;    w += (size_t)VOCAB * EMBED * 4;  // 1 MB
  _Float16* zhi  = (_Float16*)w; w += (size_t)ZR * EMBED * 2;     // 8 MB
  char*     spare = w;           w += (size_t)ZR * EMBED * 2;     // 8 MB (hdec)
  unsigned short* w1t1 = (unsigned short*)w; w += (size_t)HIDD * OBSD * 2;
  unsigned short* w1t2 = (unsigned short*)w; w += (size_t)HIDD * OBSD * 2;
  unsigned short* w1t3 = (unsigned short*)w; w += (size_t)HIDD * OBSD * 2;
  unsigned short* w2t1 = (unsigned short*)w; w += (size_t)ZD * HIDD * 2;
  unsigned short* w2t2 = (unsigned short*)w; w += (size_t)ZD * HIDD * 2;
  unsigned short* w2t3 = (unsigned short*)w; w += (size_t)ZD * HIDD * 2;
  unsigned short* d1t  = (unsigned short*)w; w += (size_t)HIDD * ZD * 2;
  unsigned short* d2t  = (unsigned short*)w; w += (size_t)OBSD * HIDD * 2;
  int* tokens = (int*)w;  w += (size_t)ZR * 4;
  int* rrows  = (int*)w;  w += (size_t)ZR * 4;
  int* rcnt   = (int*)w;  w += 64;
  float2* pb2 = (float2*)w; w += (size_t)NCHUNK * ZR * 8;         // 2 MB
  int*   pidx = (int*)w;    w += (size_t)NCHUNK * ZR * 4;         // 1 MB

  // overlays (dead-time disjoint):
  unsigned short* o1 = (unsigned short*)zhi;           // [prep..enc1]
  unsigned short* o2 = o1 + (size_t)BNR * OBSD;
  unsigned short* o3 = o2 + (size_t)BNR * OBSD;
  unsigned short* zqb  = (unsigned short*)zhi;         // [gather..dec1]
  unsigned short* hdec = (unsigned short*)spare;       // [dec1..dec2]

  prep_all_kernel<<<3216, 256, 0, stream>>>(
      cb, chi, bcol, bcold, cbT,
      ew1, w1t1, w1t2, w1t3,
      ew2, w2t1, w2t2, w2t3,
      obs, o1, o2, o3,
      dw1, d1t, dw2, d2t, rcnt);

  // enc1: 3-split, tile 32x128
  gemm_lds_kernel<3, 1, true, 0><<<dim3(BNR / 32, HIDD / 128), 512, 0, stream>>>(
      o1, o2, o3, w1t1, w1t2, w1t3, eb1, BNR, HIDD, OBSD,
      h1, h2, h3, nullptr, nullptr);
  // enc2: 3-split, tile 64x128
  gemm_lds_kernel<3, 2, false, 1><<<dim3(BNR / 64, ZD / 128), 512, 0, stream>>>(
      h1, h2, h3, w2t1, w2t2, w2t3, eb2, BNR, ZD, HIDD,
      nullptr, nullptr, nullptr, out_z, zhi);

  // dist: 32 rows/wave, hi-only 2-MFMA chain (r13)
  dist_kernel<<<dim3(ZR / 512, NCHUNK), 1024, 0, stream>>>(
      zhi, chi, bcol, pb2, pidx);
  merge_kernel<<<ZR / 256, 256, 0, stream>>>(pb2, pidx, tokens, rcnt, rrows);
  rescue_kernel<<<512, 512, 0, stream>>>(rcnt, rrows, out_z, cbT, bcold, tokens);
  gather_kernel<<<(ZR * 16) / 256, 256, 0, stream>>>(tokens, cb, out_zq, zqb);

  // dec1: plain bf16, tile 32x128
  gemm_lds_kernel<1, 1, true, 2><<<dim3(BNR / 32, HIDD / 128), 512, 0, stream>>>(
      zqb, zqb, zqb, d1t, d1t, d1t, db1, BNR, HIDD, ZD,
      hdec, nullptr, nullptr, nullptr, nullptr);
  // dec2: small, direct-load kernel
  dec_mfma_kernel<false, false><<<dim3(BNR / 64, OBSD / 64), 256, 0, stream>>>(
      hdec, d2t, db2, BNR, OBSD, HIDD, nullptr, out_rec);
}